// Round 5
// baseline (3221.112 us; speedup 1.0000x reference)
//
#include <hip/hip_runtime.h>
#include <math.h>

namespace {

typedef __attribute__((ext_vector_type(8))) short  s16x8;
typedef __attribute__((ext_vector_type(8))) unsigned short u16x8;
typedef __attribute__((ext_vector_type(4))) float  f32x4;
typedef __attribute__((address_space(1))) const unsigned int kGlobU32;
typedef __attribute__((address_space(3))) unsigned int kLdsU32;

constexpr int  Lc = 4, Cc = 8, Bc = 2048, Ec = 256, Hc = 512, NCc = 32000;
constexpr long CB      = (long)Cc * Bc;        // 16384
constexpr long HN_L    = CB * Hc;              // 8,388,608
constexpr long Y_ELEMS = (long)Bc * NCc;       // 65,536,000

__device__ __forceinline__ float b2f(unsigned short u) {
  return __uint_as_float(((unsigned int)u) << 16);
}
__device__ __forceinline__ unsigned short f2b(float x) {  // RNE
  unsigned int u = __float_as_uint(x);
  return (unsigned short)((u + 0x7fffu + ((u >> 16) & 1u)) >> 16);
}

// ---------------------------------------------------------------------------
// C[M,N] = A_bf16[M,K] @ B_f32[N,K]^T + bias[N], batched via blockIdx.z.
// 128x128 tile, BK=32, 256 thr = 4 waves (2x2), each wave 64x64 via 4x4
// frags of mfma_f32_16x16x32_bf16 (C/D: col=lane&15, row=(lane>>4)*4+reg).
// A staged with global_load_lds(16B) into linear [row][k] LDS; B reg-staged
// fp32->bf16 (RNE). Double-buffered LDS, 1 barrier per K-step, next-tile
// staging overlaps compute.
// ---------------------------------------------------------------------------
template<bool BF16_OUT>
__global__ __launch_bounds__(256) void gemm_bt(
    const unsigned short* __restrict__ A, const float* __restrict__ B,
    const float* __restrict__ bias, void* __restrict__ Cv,
    int M, int N, int K, long sA, long sB, long sBias, long sC)
{
  __shared__ unsigned short As[2][4096];   // [row0..127][k0..31]
  __shared__ unsigned short Bs[2][4096];   // [col0..127][k0..31]
  const int tid  = threadIdx.x;
  const int lane = tid & 63, w = tid >> 6;
  const long zb = blockIdx.z;
  A += zb * sA; B += zb * sB;
  const float* bp = bias + zb * sBias;
  const int row0 = blockIdx.y * 128, col0 = blockIdx.x * 128;
  const int nk = K >> 5;

  // A staging map: flat elem e = s*2048 + w*512 + lane*8 -> row=e/32, k=e%32
  const long aRow = (long)(row0 + w * 16 + (lane >> 2));
  const int  ak0  = (lane & 3) * 8;

  // B staging map: thread -> col=tid>>1, k-half=(tid&1)*16
  const int bcol = tid >> 1, bkh = (tid & 1) * 16;
  const float* Bg = B + (long)(col0 + bcol) * K + bkh;
  unsigned short* BsD0 = &Bs[0][bcol * 32 + bkh];
  unsigned short* BsD1 = &Bs[1][bcol * 32 + bkh];

  f32x4 acc[4][4];
#pragma unroll
  for (int m = 0; m < 4; ++m)
#pragma unroll
    for (int n = 0; n < 4; ++n) acc[m][n] = {0.f, 0.f, 0.f, 0.f};

  const int wr = (w >> 1) * 64, wc = (w & 1) * 64;
  const int fr = lane & 15, fg = lane >> 4;

  auto stageA = [&](int kt, int buf) {
    const unsigned short* g0 = A + aRow * K + kt * 32 + ak0;
    const unsigned short* g1 = g0 + (long)64 * K;
    __builtin_amdgcn_global_load_lds((kGlobU32*)g0,
        (kLdsU32*)&As[buf][w * 512],        16, 0, 0);
    __builtin_amdgcn_global_load_lds((kGlobU32*)g1,
        (kLdsU32*)&As[buf][2048 + w * 512], 16, 0, 0);
  };
  auto loadB = [&](float4* r, int kt) {
    const float* p = Bg + kt * 32;
    r[0] = *(const float4*)(p);
    r[1] = *(const float4*)(p + 4);
    r[2] = *(const float4*)(p + 8);
    r[3] = *(const float4*)(p + 12);
  };
  auto writeB = [&](unsigned short* d, const float4* r) {
    union { unsigned short u[16]; uint4 q[2]; } t;
#pragma unroll
    for (int i = 0; i < 16; ++i) t.u[i] = f2b(((const float*)r)[i]);
    *(uint4*)(d)     = t.q[0];
    *(uint4*)(d + 8) = t.q[1];
  };
  auto compute = [&](int buf) {
    s16x8 af[4], bfr[4];
#pragma unroll
    for (int m = 0; m < 4; ++m)
      af[m]  = *(const s16x8*)&As[buf][(wr + m * 16 + fr) * 32 + fg * 8];
#pragma unroll
    for (int n = 0; n < 4; ++n)
      bfr[n] = *(const s16x8*)&Bs[buf][(wc + n * 16 + fr) * 32 + fg * 8];
#pragma unroll
    for (int m = 0; m < 4; ++m)
#pragma unroll
      for (int n = 0; n < 4; ++n)
        acc[m][n] = __builtin_amdgcn_mfma_f32_16x16x32_bf16(af[m], bfr[n], acc[m][n], 0, 0, 0);
  };

  float4 rb0[4], rb1[4];
  loadB(rb0, 0);
  stageA(0, 0);
  writeB(BsD0, rb0);            // compiler inserts vmcnt wait for rb0
  if (1 < nk) loadB(rb1, 1);

  int kt = 0;
  for (;;) {
    __syncthreads();            // buf0 staged / prior buf0 readers done
    if (kt + 1 < nk) { stageA(kt + 1, 1); writeB(BsD1, rb1); }
    if (kt + 2 < nk) loadB(rb0, kt + 2);
    compute(0);
    if (++kt >= nk) break;
    __syncthreads();
    if (kt + 1 < nk) { stageA(kt + 1, 0); writeB(BsD0, rb0); }
    if (kt + 2 < nk) loadB(rb1, kt + 2);
    compute(1);
    if (++kt >= nk) break;
  }

  float bv[4];
#pragma unroll
  for (int n = 0; n < 4; ++n) bv[n] = bp[col0 + wc + n * 16 + fr];
#pragma unroll
  for (int m = 0; m < 4; ++m)
#pragma unroll
    for (int n = 0; n < 4; ++n)
#pragma unroll
      for (int r = 0; r < 4; ++r) {
        const long row = row0 + wr + m * 16 + fg * 4 + r;
        const long col = col0 + wc + n * 16 + fr;
        const float v = acc[m][n][r] + bv[n];
        if (BF16_OUT) ((unsigned short*)Cv)[zb * sC + row * N + col] = f2b(v);
        else          ((float*)Cv)[zb * sC + row * N + col] = v;
      }
}

// ---------------------------------------------------------------------------
// f32 -> bf16 bulk convert (units of 8 elements)
// ---------------------------------------------------------------------------
__global__ __launch_bounds__(256) void f2b_all(
    const float* __restrict__ in, unsigned short* __restrict__ out, long n8)
{
  const long i = (long)blockIdx.x * 256 + threadIdx.x;
  if (i >= n8) return;
  const float4 a = ((const float4*)in)[2 * i];
  const float4 b = ((const float4*)in)[2 * i + 1];
  u16x8 o;
  o[0] = f2b(a.x); o[1] = f2b(a.y); o[2] = f2b(a.z); o[3] = f2b(a.w);
  o[4] = f2b(b.x); o[5] = f2b(b.y); o[6] = f2b(b.z); o[7] = f2b(b.w);
  *(u16x8*)(out + i * 8) = o;
}

// ---------------------------------------------------------------------------
// MHA core: qkv_bf16 (16384 x 1536) -> o_bf16 (16384 x 512). Block per b.
// ---------------------------------------------------------------------------
__global__ __launch_bounds__(256) void attn_kernel(
    const unsigned short* __restrict__ qkv, unsigned short* __restrict__ o)
{
  const int b = blockIdx.x, tid = threadIdx.x;
  __shared__ float q_s[8][520], k_s[8][520], v_s[8][520];
  __shared__ float sc[8][8][8];

  for (int i8 = tid; i8 < 1536; i8 += 256) {
    const int s = i8 / 192, f = (i8 % 192) * 8;
    const u16x8 u = *(const u16x8*)(qkv + ((long)(s * 2048 + b)) * 1536 + f);
    float* dst = (f < 512) ? &q_s[s][f] : ((f < 1024) ? &k_s[s][f - 512] : &v_s[s][f - 1024]);
#pragma unroll
    for (int j = 0; j < 8; ++j) dst[j] = b2f(u[j]);
  }
  __syncthreads();

  for (int idx = tid; idx < 512; idx += 256) {
    const int hh = idx >> 6, s = (idx >> 3) & 7, t = idx & 7;
    float a = 0.0f;
#pragma unroll
    for (int d = 0; d < 64; ++d) a += q_s[s][hh * 64 + d] * k_s[t][hh * 64 + d];
    sc[hh][s][t] = a * 0.125f;
  }
  __syncthreads();

  if (tid < 64) {
    const int hh = tid >> 3, s = tid & 7;
    float m = sc[hh][s][0];
#pragma unroll
    for (int t = 1; t < 8; ++t) m = fmaxf(m, sc[hh][s][t]);
    float e[8], sum = 0.0f;
#pragma unroll
    for (int t = 0; t < 8; ++t) { e[t] = expf(sc[hh][s][t] - m); sum += e[t]; }
    const float inv = 1.0f / sum;
#pragma unroll
    for (int t = 0; t < 8; ++t) sc[hh][s][t] = e[t] * inv;
  }
  __syncthreads();

  for (int i = tid; i < 4096; i += 256) {
    const int s = i >> 9, f = i & 511, hh = f >> 6;
    float a = 0.0f;
#pragma unroll
    for (int t = 0; t < 8; ++t) a += sc[hh][s][t] * v_s[t][f];
    o[((long)(s * 2048 + b)) * 512 + f] = f2b(a);
  }
}

// ---------------------------------------------------------------------------
// LayerNorm rows of 512: reads fp32, writes bf16.
// ---------------------------------------------------------------------------
__global__ __launch_bounds__(256) void ln_kernel(
    const float* __restrict__ x, const float* __restrict__ g,
    const float* __restrict__ bb, unsigned short* __restrict__ xb)
{
  const long row = blockIdx.x;
  const float* p = x + row * 512;
  const int tid = threadIdx.x;
  const float v0 = p[tid], v1 = p[tid + 256];
  float s = v0 + v1, ss = v0 * v0 + v1 * v1;
#pragma unroll
  for (int m = 32; m >= 1; m >>= 1) { s += __shfl_xor(s, m); ss += __shfl_xor(ss, m); }
  __shared__ float red[8];
  const int wid = tid >> 6;
  if ((tid & 63) == 0) { red[wid] = s; red[4 + wid] = ss; }
  __syncthreads();
  const float S  = red[0] + red[1] + red[2] + red[3];
  const float SS = red[4] + red[5] + red[6] + red[7];
  const float mu  = S * (1.0f / 512.0f);
  const float var = SS * (1.0f / 512.0f) - mu * mu;
  const float inv = 1.0f / sqrtf(var + 1e-5f);
  xb[row * 512 + tid]       = f2b((v0 - mu) * inv * g[tid]       + bb[tid]);
  xb[row * 512 + tid + 256] = f2b((v1 - mu) * inv * g[tid + 256] + bb[tid + 256]);
}

// ---------------------------------------------------------------------------
// xin builders (bf16). L0: [embed(c==0)|msg] -> 768. L>0: [hn_prev|msg] -> 1024.
// ---------------------------------------------------------------------------
__global__ __launch_bounds__(256) void build_xin0(
    const int* __restrict__ tokens, const float* __restrict__ embed,
    const unsigned short* __restrict__ msgb, unsigned short* __restrict__ xin)
{
  const long i = (long)blockIdx.x * 256 + threadIdx.x;   // < CB*96
  const long cb = i / 96; const int u = (int)(i % 96);
  const int c = (int)(cb >> 11), b = (int)(cb & 2047);
  u16x8 v;
  if (u < 32) {
    if (c == 0) {
      const float* e = embed + (long)tokens[b] * 256 + u * 8;
#pragma unroll
      for (int j = 0; j < 8; ++j) v[j] = f2b(e[j]);
    } else {
#pragma unroll
      for (int j = 0; j < 8; ++j) v[j] = 0;
    }
  } else {
    v = *(const u16x8*)(msgb + cb * 512 + (long)(u - 32) * 8);
  }
  *(u16x8*)(xin + cb * 768 + (long)u * 8) = v;
}

__global__ __launch_bounds__(256) void build_xin(
    const unsigned short* __restrict__ hnb, const unsigned short* __restrict__ msgb,
    unsigned short* __restrict__ xin)
{
  const long i = (long)blockIdx.x * 256 + threadIdx.x;   // < CB*128
  const long cb = i >> 7; const int u = (int)(i & 127);
  u16x8 v;
  if (u < 64) v = *(const u16x8*)(hnb  + cb * 512 + (long)u * 8);
  else        v = *(const u16x8*)(msgb + cb * 512 + (long)(u - 64) * 8);
  *(u16x8*)(xin + cb * 1024 + (long)u * 8) = v;
}

// ---------------------------------------------------------------------------
// GRU gate: reads bf16 gi/gh, fp32 h; writes fp32 hn (d_out) + bf16 copy.
// ---------------------------------------------------------------------------
__global__ __launch_bounds__(256) void gru_gate(
    const unsigned short* __restrict__ gi, const unsigned short* __restrict__ gh,
    const float* __restrict__ h, float* __restrict__ hn, unsigned short* __restrict__ hnb)
{
  const long i = (long)blockIdx.x * 256 + threadIdx.x;   // < CB*64
  const long cb = i >> 6;
  const int  j = (int)(i & 63) * 8;
  const unsigned short* gir = gi + cb * 1536 + j;
  const unsigned short* ghr = gh + cb * 1536 + j;
  const u16x8 ir = *(const u16x8*)gir,  iz = *(const u16x8*)(gir + 512),  in_ = *(const u16x8*)(gir + 1024);
  const u16x8 hr = *(const u16x8*)ghr,  hz = *(const u16x8*)(ghr + 512),  hn_ = *(const u16x8*)(ghr + 1024);
  union { float4 q[2]; float f[8]; } hv, out;
  hv.q[0] = ((const float4*)(h + cb * 512 + j))[0];
  hv.q[1] = ((const float4*)(h + cb * 512 + j))[1];
  u16x8 ob;
#pragma unroll
  for (int k = 0; k < 8; ++k) {
    const float r = 1.0f / (1.0f + expf(-(b2f(ir[k]) + b2f(hr[k]))));
    const float z = 1.0f / (1.0f + expf(-(b2f(iz[k]) + b2f(hz[k]))));
    const float n = tanhf(b2f(in_[k]) + r * b2f(hn_[k]));
    const float o = (1.0f - z) * n + z * hv.f[k];
    out.f[k] = o; ob[k] = f2b(o);
  }
  ((float4*)(hn + cb * 512 + j))[0] = out.q[0];
  ((float4*)(hn + cb * 512 + j))[1] = out.q[1];
  *(u16x8*)(hnb + cb * 512 + j) = ob;
}

}  // namespace

extern "C" void kernel_launch(void* const* d_in, const int* in_sizes, int n_in,
                              void* d_out, int out_size, void* d_ws, size_t ws_size,
                              hipStream_t stream)
{
  const int*   tokens    = (const int*)  d_in[0];
  const float* h         = (const float*)d_in[1];
  const float* embed     = (const float*)d_in[2];
  const float* W_ih0     = (const float*)d_in[3];
  const float* W_ih_rest = (const float*)d_in[4];
  const float* W_hh      = (const float*)d_in[5];
  const float* b_ih      = (const float*)d_in[6];
  const float* b_hh      = (const float*)d_in[7];
  const float* aw_in     = (const float*)d_in[8];
  const float* ab_in     = (const float*)d_in[9];
  const float* aw_out    = (const float*)d_in[10];
  const float* ab_out    = (const float*)d_in[11];
  const float* ln_g      = (const float*)d_in[12];
  const float* ln_b      = (const float*)d_in[13];
  const float* head_w    = (const float*)d_in[14];
  const float* head_b    = (const float*)d_in[15];

  float* y  = (float*)d_out;
  float* hn = (float*)d_out + Y_ELEMS;

  // workspace layout (bytes), total 285,212,672 (~285 MB)
  char* w = (char*)d_ws;
  unsigned short* h_bf   = (unsigned short*)(w);                  //  67,108,864 B
  unsigned short* qkv_bf = (unsigned short*)(w + 67108864);       //  50,331,648 B (union gi_bf)
  unsigned short* gi_bf  = qkv_bf;
  unsigned short* gh_bf  = (unsigned short*)(w + 117440512);      //  50,331,648 B
  unsigned short* o_bf   = (unsigned short*)(w + 167772160);      //  16,777,216 B
  float*          msg    = (float*)        (w + 184549376);       //  33,554,432 B
  unsigned short* msg_bf = (unsigned short*)(w + 218103808);      //  16,777,216 B
  unsigned short* xin_bf = (unsigned short*)(w + 234881024);      //  33,554,432 B
  unsigned short* hn_bf  = (unsigned short*)(w + 268435456);      //  16,777,216 B

  // h (all layers) -> bf16 once
  f2b_all<<<16384, 256, 0, stream>>>(h, h_bf, (long)Lc * HN_L / 8);

  for (int l = 0; l < Lc; ++l) {
    const unsigned short* hl_bf = h_bf + (long)l * HN_L;

    // qkv = h[l] @ w_in[l]^T + b_in[l]  (16384x1536, K=512) -> bf16
    gemm_bt<true><<<dim3(12, 128, 1), 256, 0, stream>>>(
        hl_bf, aw_in + (long)l * 1536 * 512, ab_in + (long)l * 1536, qkv_bf,
        (int)CB, 1536, 512, 0, 0, 0, 0);

    attn_kernel<<<2048, 256, 0, stream>>>(qkv_bf, o_bf);

    // msg_pre = o @ w_out[l]^T + b_out[l]  (16384x512, K=512) -> fp32
    gemm_bt<false><<<dim3(4, 128, 1), 256, 0, stream>>>(
        o_bf, aw_out + (long)l * 512 * 512, ab_out + (long)l * 512, msg,
        (int)CB, 512, 512, 0, 0, 0, 0);

    ln_kernel<<<(int)CB, 256, 0, stream>>>(msg, ln_g + (long)l * 512, ln_b + (long)l * 512, msg_bf);

    int xd;
    const float* Wih;
    if (l == 0) {
      xd = Ec + Hc;  // 768
      Wih = W_ih0;
      build_xin0<<<6144, 256, 0, stream>>>(tokens, embed, msg_bf, xin_bf);
    } else {
      xd = 2 * Hc;   // 1024
      Wih = W_ih_rest + (long)(l - 1) * Cc * 1536 * 1024;
      build_xin<<<8192, 256, 0, stream>>>(hn_bf, msg_bf, xin_bf);
    }

    // gi = xin @ Wih^T + b_ih[l]  batched z=8 (2048x1536, K=xd) -> bf16
    gemm_bt<true><<<dim3(12, 16, 8), 256, 0, stream>>>(
        xin_bf, Wih, b_ih + (long)l * Cc * 1536, gi_bf,
        Bc, 1536, xd, (long)Bc * xd, (long)1536 * xd, 1536, (long)Bc * 1536);

    // gh = h[l] @ W_hh[l]^T + b_hh[l]  batched z=8 (2048x1536, K=512) -> bf16
    gemm_bt<true><<<dim3(12, 16, 8), 256, 0, stream>>>(
        hl_bf, W_hh + (long)l * Cc * 1536 * 512, b_hh + (long)l * Cc * 1536, gh_bf,
        Bc, 1536, 512, (long)Bc * 512, (long)1536 * 512, 1536, (long)Bc * 1536);

    gru_gate<<<4096, 256, 0, stream>>>(gi_bf, gh_bf, h + (long)l * HN_L,
                                       hn + (long)l * HN_L, hn_bf);
  }

  // y = h_n[3][0] @ head_w^T + head_b  (2048x32000, K=512) -> fp32
  gemm_bt<false><<<dim3(250, 16, 1), 256, 0, stream>>>(
      hn_bf, head_w, head_b, y,
      Bc, NCc, 512, 0, 0, 0, 0);
}

// Round 6
// 1805.204 us; speedup vs baseline: 1.7843x; 1.7843x over previous
//
#include <hip/hip_runtime.h>
#include <math.h>

namespace {

typedef __attribute__((ext_vector_type(8))) short  s16x8;
typedef __attribute__((ext_vector_type(8))) unsigned short u16x8;
typedef __attribute__((ext_vector_type(4))) float  f32x4;
typedef __attribute__((address_space(1))) const unsigned int kGlobU32;
typedef __attribute__((address_space(3))) unsigned int kLdsU32;

constexpr int  Lc = 4, Cc = 8, Bc = 2048, Ec = 256, Hc = 512, NCc = 32000;
constexpr long CB      = (long)Cc * Bc;        // 16384
constexpr long HN_L    = CB * Hc;              // 8,388,608
constexpr long Y_ELEMS = (long)Bc * NCc;       // 65,536,000

__device__ __forceinline__ float b2f(unsigned short u) {
  return __uint_as_float(((unsigned int)u) << 16);
}
__device__ __forceinline__ unsigned short f2b(float x) {  // RNE
  unsigned int u = __float_as_uint(x);
  return (unsigned short)((u + 0x7fffu + ((u >> 16) & 1u)) >> 16);
}

// ---------------------------------------------------------------------------
// C[M,N] = A_bf16[M,K] @ B_bf16[N,K]^T + bias_f32[N], batched via blockIdx.z.
// m97 structure: 128x128 tile, BK=32, 256 thr = 4 waves (2x2), 4x4 frags of
// mfma_f32_16x16x32_bf16 (C/D: col=lane&15, row=(lane>>4)*4+reg).
// Both A and B staged via global_load_lds(16B) into linear [row][32k] LDS.
// Double-buffered, 1 barrier per K-step (barrier's vmcnt drain = the fence).
// SWAPXY puts row-tiles on blockIdx.x (L2 reuse of B when N >> M, e.g. head).
// ---------------------------------------------------------------------------
template<bool BF16_OUT, bool SWAPXY>
__global__ __launch_bounds__(256) void gemm_bb(
    const unsigned short* __restrict__ A, const unsigned short* __restrict__ B,
    const float* __restrict__ bias, void* __restrict__ Cv,
    int N, int K, long sA, long sB, long sBias, long sC)
{
  __shared__ unsigned short As[2][4096];   // [row0..127][k0..31]
  __shared__ unsigned short Bs[2][4096];   // [col0..127][k0..31]
  const int tid  = threadIdx.x;
  const int lane = tid & 63, w = tid >> 6;
  const long zb = blockIdx.z;
  A += zb * sA; B += zb * sB;
  const float* bp = bias + zb * sBias;
  const int row0 = (SWAPXY ? blockIdx.x : blockIdx.y) * 128;
  const int col0 = (SWAPXY ? blockIdx.y : blockIdx.x) * 128;
  const int nk = K >> 5;

  // staging map: wave w, lane l -> LDS shorts [w*512 + l*8, +8)
  //   = tile row (w*16 + (l>>2)) (+64 for second half), k = (l&3)*8..+8
  const int srow = w * 16 + (lane >> 2);
  const int sk0  = (lane & 3) * 8;
  const unsigned short* Ag = A + (long)(row0 + srow) * K + sk0;
  const unsigned short* Bg = B + (long)(col0 + srow) * K + sk0;

  f32x4 acc[4][4];
#pragma unroll
  for (int m = 0; m < 4; ++m)
#pragma unroll
    for (int n = 0; n < 4; ++n) acc[m][n] = {0.f, 0.f, 0.f, 0.f};

  const int wr = (w >> 1) * 64, wc = (w & 1) * 64;
  const int fr = lane & 15, fg = lane >> 4;

  auto stage = [&](int kt, int buf) {
    const unsigned short* a0 = Ag + kt * 32;
    const unsigned short* b0 = Bg + kt * 32;
    __builtin_amdgcn_global_load_lds((kGlobU32*)a0,
        (kLdsU32*)&As[buf][w * 512],        16, 0, 0);
    __builtin_amdgcn_global_load_lds((kGlobU32*)(a0 + (long)64 * K),
        (kLdsU32*)&As[buf][2048 + w * 512], 16, 0, 0);
    __builtin_amdgcn_global_load_lds((kGlobU32*)b0,
        (kLdsU32*)&Bs[buf][w * 512],        16, 0, 0);
    __builtin_amdgcn_global_load_lds((kGlobU32*)(b0 + (long)64 * K),
        (kLdsU32*)&Bs[buf][2048 + w * 512], 16, 0, 0);
  };
  auto compute = [&](int buf) {
    s16x8 af[4], bfr[4];
#pragma unroll
    for (int m = 0; m < 4; ++m)
      af[m]  = *(const s16x8*)&As[buf][(wr + m * 16 + fr) * 32 + fg * 8];
#pragma unroll
    for (int n = 0; n < 4; ++n)
      bfr[n] = *(const s16x8*)&Bs[buf][(wc + n * 16 + fr) * 32 + fg * 8];
#pragma unroll
    for (int m = 0; m < 4; ++m)
#pragma unroll
      for (int n = 0; n < 4; ++n)
        acc[m][n] = __builtin_amdgcn_mfma_f32_16x16x32_bf16(af[m], bfr[n], acc[m][n], 0, 0, 0);
  };

  stage(0, 0);
  for (int kt = 0; kt < nk; ++kt) {
    const int cur = kt & 1;
    __syncthreads();   // drains vmcnt (stage(kt) landed) + WAR vs prev compute
    if (kt + 1 < nk) stage(kt + 1, cur ^ 1);
    compute(cur);
  }

  float bv[4];
#pragma unroll
  for (int n = 0; n < 4; ++n) bv[n] = bp[col0 + wc + n * 16 + fr];
#pragma unroll
  for (int m = 0; m < 4; ++m)
#pragma unroll
    for (int n = 0; n < 4; ++n)
#pragma unroll
      for (int r = 0; r < 4; ++r) {
        const long row = row0 + wr + m * 16 + fg * 4 + r;
        const long col = col0 + wc + n * 16 + fr;
        const float v = acc[m][n][r] + bv[n];
        if (BF16_OUT) ((unsigned short*)Cv)[zb * sC + row * N + col] = f2b(v);
        else          ((float*)Cv)[zb * sC + row * N + col] = v;
      }
}

// ---------------------------------------------------------------------------
// f32 -> bf16 bulk convert (units of 8 elements)
// ---------------------------------------------------------------------------
__global__ __launch_bounds__(256) void f2b_all(
    const float* __restrict__ in, unsigned short* __restrict__ out, long n8)
{
  const long i = (long)blockIdx.x * 256 + threadIdx.x;
  if (i >= n8) return;
  const float4 a = ((const float4*)in)[2 * i];
  const float4 b = ((const float4*)in)[2 * i + 1];
  u16x8 o;
  o[0] = f2b(a.x); o[1] = f2b(a.y); o[2] = f2b(a.z); o[3] = f2b(a.w);
  o[4] = f2b(b.x); o[5] = f2b(b.y); o[6] = f2b(b.z); o[7] = f2b(b.w);
  *(u16x8*)(out + i * 8) = o;
}

// ---------------------------------------------------------------------------
// MHA core: qkv_bf16 (16384 x 1536) -> o_bf16 (16384 x 512). Block per b.
// ---------------------------------------------------------------------------
__global__ __launch_bounds__(256) void attn_kernel(
    const unsigned short* __restrict__ qkv, unsigned short* __restrict__ o)
{
  const int b = blockIdx.x, tid = threadIdx.x;
  __shared__ float q_s[8][520], k_s[8][520], v_s[8][520];
  __shared__ float sc[8][8][8];

  for (int i8 = tid; i8 < 1536; i8 += 256) {
    const int s = i8 / 192, f = (i8 % 192) * 8;
    const u16x8 u = *(const u16x8*)(qkv + ((long)(s * 2048 + b)) * 1536 + f);
    float* dst = (f < 512) ? &q_s[s][f] : ((f < 1024) ? &k_s[s][f - 512] : &v_s[s][f - 1024]);
#pragma unroll
    for (int j = 0; j < 8; ++j) dst[j] = b2f(u[j]);
  }
  __syncthreads();

  for (int idx = tid; idx < 512; idx += 256) {
    const int hh = idx >> 6, s = (idx >> 3) & 7, t = idx & 7;
    float a = 0.0f;
#pragma unroll
    for (int d = 0; d < 64; ++d) a += q_s[s][hh * 64 + d] * k_s[t][hh * 64 + d];
    sc[hh][s][t] = a * 0.125f;
  }
  __syncthreads();

  if (tid < 64) {
    const int hh = tid >> 3, s = tid & 7;
    float m = sc[hh][s][0];
#pragma unroll
    for (int t = 1; t < 8; ++t) m = fmaxf(m, sc[hh][s][t]);
    float e[8], sum = 0.0f;
#pragma unroll
    for (int t = 0; t < 8; ++t) { e[t] = expf(sc[hh][s][t] - m); sum += e[t]; }
    const float inv = 1.0f / sum;
#pragma unroll
    for (int t = 0; t < 8; ++t) sc[hh][s][t] = e[t] * inv;
  }
  __syncthreads();

  for (int i = tid; i < 4096; i += 256) {
    const int s = i >> 9, f = i & 511, hh = f >> 6;
    float a = 0.0f;
#pragma unroll
    for (int t = 0; t < 8; ++t) a += sc[hh][s][t] * v_s[t][f];
    o[((long)(s * 2048 + b)) * 512 + f] = f2b(a);
  }
}

// ---------------------------------------------------------------------------
// LayerNorm rows of 512, bf16 in-place (per-thread in/out, no cross-read).
// ---------------------------------------------------------------------------
__global__ __launch_bounds__(256) void ln_bf(
    unsigned short* __restrict__ x, const float* __restrict__ g,
    const float* __restrict__ bb)
{
  const long row = blockIdx.x;
  unsigned short* p = x + row * 512;
  const int tid = threadIdx.x;
  const float v0 = b2f(p[tid]), v1 = b2f(p[tid + 256]);
  float s = v0 + v1, ss = v0 * v0 + v1 * v1;
#pragma unroll
  for (int m = 32; m >= 1; m >>= 1) { s += __shfl_xor(s, m); ss += __shfl_xor(ss, m); }
  __shared__ float red[8];
  const int wid = tid >> 6;
  if ((tid & 63) == 0) { red[wid] = s; red[4 + wid] = ss; }
  __syncthreads();
  const float S  = red[0] + red[1] + red[2] + red[3];
  const float SS = red[4] + red[5] + red[6] + red[7];
  const float mu  = S * (1.0f / 512.0f);
  const float var = SS * (1.0f / 512.0f) - mu * mu;
  const float inv = 1.0f / sqrtf(var + 1e-5f);
  p[tid]       = f2b((v0 - mu) * inv * g[tid]       + bb[tid]);
  p[tid + 256] = f2b((v1 - mu) * inv * g[tid + 256] + bb[tid + 256]);
}

// ---------------------------------------------------------------------------
// xin builders (bf16). L0: [embed(c==0)|msg] -> 768. L>0: [hn_prev|msg] -> 1024.
// ---------------------------------------------------------------------------
__global__ __launch_bounds__(256) void build_xin0(
    const int* __restrict__ tokens, const float* __restrict__ embed,
    const unsigned short* __restrict__ msgb, unsigned short* __restrict__ xin)
{
  const long i = (long)blockIdx.x * 256 + threadIdx.x;   // < CB*96
  const long cb = i / 96; const int u = (int)(i % 96);
  const int c = (int)(cb >> 11), b = (int)(cb & 2047);
  u16x8 v;
  if (u < 32) {
    if (c == 0) {
      const float* e = embed + (long)tokens[b] * 256 + u * 8;
#pragma unroll
      for (int j = 0; j < 8; ++j) v[j] = f2b(e[j]);
    } else {
#pragma unroll
      for (int j = 0; j < 8; ++j) v[j] = 0;
    }
  } else {
    v = *(const u16x8*)(msgb + cb * 512 + (long)(u - 32) * 8);
  }
  *(u16x8*)(xin + cb * 768 + (long)u * 8) = v;
}

__global__ __launch_bounds__(256) void build_xin(
    const unsigned short* __restrict__ hnb, const unsigned short* __restrict__ msgb,
    unsigned short* __restrict__ xin)
{
  const long i = (long)blockIdx.x * 256 + threadIdx.x;   // < CB*128
  const long cb = i >> 7; const int u = (int)(i & 127);
  u16x8 v;
  if (u < 64) v = *(const u16x8*)(hnb  + cb * 512 + (long)u * 8);
  else        v = *(const u16x8*)(msgb + cb * 512 + (long)(u - 64) * 8);
  *(u16x8*)(xin + cb * 1024 + (long)u * 8) = v;
}

// ---------------------------------------------------------------------------
// GRU gate: reads bf16 gi/gh, fp32 h; writes fp32 hn (d_out) + bf16 copy.
// ---------------------------------------------------------------------------
__global__ __launch_bounds__(256) void gru_gate(
    const unsigned short* __restrict__ gi, const unsigned short* __restrict__ gh,
    const float* __restrict__ h, float* __restrict__ hn, unsigned short* __restrict__ hnb)
{
  const long i = (long)blockIdx.x * 256 + threadIdx.x;   // < CB*64
  const long cb = i >> 6;
  const int  j = (int)(i & 63) * 8;
  const unsigned short* gir = gi + cb * 1536 + j;
  const unsigned short* ghr = gh + cb * 1536 + j;
  const u16x8 ir = *(const u16x8*)gir,  iz = *(const u16x8*)(gir + 512),  in_ = *(const u16x8*)(gir + 1024);
  const u16x8 hr = *(const u16x8*)ghr,  hz = *(const u16x8*)(ghr + 512),  hn_ = *(const u16x8*)(ghr + 1024);
  union { float4 q[2]; float f[8]; } hv, out;
  hv.q[0] = ((const float4*)(h + cb * 512 + j))[0];
  hv.q[1] = ((const float4*)(h + cb * 512 + j))[1];
  u16x8 ob;
#pragma unroll
  for (int k = 0; k < 8; ++k) {
    const float r = 1.0f / (1.0f + expf(-(b2f(ir[k]) + b2f(hr[k]))));
    const float z = 1.0f / (1.0f + expf(-(b2f(iz[k]) + b2f(hz[k]))));
    const float n = tanhf(b2f(in_[k]) + r * b2f(hn_[k]));
    const float o = (1.0f - z) * n + z * hv.f[k];
    out.f[k] = o; ob[k] = f2b(o);
  }
  ((float4*)(hn + cb * 512 + j))[0] = out.q[0];
  ((float4*)(hn + cb * 512 + j))[1] = out.q[1];
  *(u16x8*)(hnb + cb * 512 + j) = ob;
}

}  // namespace

extern "C" void kernel_launch(void* const* d_in, const int* in_sizes, int n_in,
                              void* d_out, int out_size, void* d_ws, size_t ws_size,
                              hipStream_t stream)
{
  const int*   tokens    = (const int*)  d_in[0];
  const float* h         = (const float*)d_in[1];
  const float* embed     = (const float*)d_in[2];
  const float* W_ih0     = (const float*)d_in[3];
  const float* W_ih_rest = (const float*)d_in[4];
  const float* W_hh      = (const float*)d_in[5];
  const float* b_ih      = (const float*)d_in[6];
  const float* b_hh      = (const float*)d_in[7];
  const float* aw_in     = (const float*)d_in[8];
  const float* ab_in     = (const float*)d_in[9];
  const float* aw_out    = (const float*)d_in[10];
  const float* ab_out    = (const float*)d_in[11];
  const float* ln_g      = (const float*)d_in[12];
  const float* ln_b      = (const float*)d_in[13];
  const float* head_w    = (const float*)d_in[14];
  const float* head_b    = (const float*)d_in[15];

  float* y  = (float*)d_out;
  float* hn = (float*)d_out + Y_ELEMS;

  // workspace layout (bytes), total 243,269,632 (~243 MB; round-5 proved >=285 OK)
  char* w = (char*)d_ws;
  unsigned short* wbuf   = (unsigned short*)(w);                  // 41,943,040 B rotating weights
  unsigned short* h_bfl  = (unsigned short*)(w + 41943040);       // 16,777,216 B (per-layer h)
  unsigned short* qkv_bf = (unsigned short*)(w + 58720256);       // 50,331,648 B (union gi_bf)
  unsigned short* gi_bf  = qkv_bf;
  unsigned short* gh_bf  = (unsigned short*)(w + 109051904);      // 50,331,648 B
  unsigned short* o_bf   = (unsigned short*)(w + 159383552);      // 16,777,216 B
  unsigned short* msg_bf = (unsigned short*)(w + 176160768);      // 16,777,216 B
  unsigned short* xin_bf = (unsigned short*)(w + 192937984);      // 33,554,432 B
  unsigned short* hn_bf  = (unsigned short*)(w + 226492416);      // 16,777,216 B

  // rotating weight sub-buffers (u16 element offsets)
  unsigned short* wih_bf   = wbuf;                 // <= 12,582,912 elems
  unsigned short* whh_bf   = wbuf + 12582912;      //     6,291,456 elems
  unsigned short* awin_bf  = wbuf + 18874368;      //       786,432 elems
  unsigned short* awout_bf = wbuf + 19660800;      //       262,144 elems
  unsigned short* headw_bf = wbuf;                 //    16,384,000 elems (after layers)

  for (int l = 0; l < Lc; ++l) {
    // per-layer conversions (fp32 -> bf16, RNE — identical rounding to round 5)
    f2b_all<<<4096, 256, 0, stream>>>(h + (long)l * HN_L, h_bfl, 1048576);
    f2b_all<<<384,  256, 0, stream>>>(aw_in  + (long)l * 786432, awin_bf, 98304);
    f2b_all<<<128,  256, 0, stream>>>(aw_out + (long)l * 262144, awout_bf, 32768);
    int xd;
    if (l == 0) {
      xd = Ec + Hc;  // 768
      f2b_all<<<4608, 256, 0, stream>>>(W_ih0, wih_bf, 1179648);
    } else {
      xd = 2 * Hc;   // 1024
      f2b_all<<<6144, 256, 0, stream>>>(W_ih_rest + (long)(l - 1) * 12582912, wih_bf, 1572864);
    }
    f2b_all<<<3072, 256, 0, stream>>>(W_hh + (long)l * 6291456, whh_bf, 786432);

    // qkv = h[l] @ w_in[l]^T + b_in[l]  (16384x1536, K=512) -> bf16
    gemm_bb<true, false><<<dim3(12, 128, 1), 256, 0, stream>>>(
        h_bfl, awin_bf, ab_in + (long)l * 1536, qkv_bf, 1536, 512, 0, 0, 0, 0);

    attn_kernel<<<2048, 256, 0, stream>>>(qkv_bf, o_bf);

    // msg = o @ w_out[l]^T + b_out[l]  (16384x512, K=512) -> bf16, LN in-place
    gemm_bb<true, false><<<dim3(4, 128, 1), 256, 0, stream>>>(
        o_bf, awout_bf, ab_out + (long)l * 512, msg_bf, 512, 512, 0, 0, 0, 0);

    ln_bf<<<(int)CB, 256, 0, stream>>>(msg_bf, ln_g + (long)l * 512, ln_b + (long)l * 512);

    if (l == 0) build_xin0<<<6144, 256, 0, stream>>>(tokens, embed, msg_bf, xin_bf);
    else        build_xin<<<8192, 256, 0, stream>>>(hn_bf, msg_bf, xin_bf);

    // gi = xin @ Wih^T + b_ih[l]  batched z=8 (2048x1536, K=xd) -> bf16
    gemm_bb<true, false><<<dim3(12, 16, 8), 256, 0, stream>>>(
        xin_bf, wih_bf, b_ih + (long)l * Cc * 1536, gi_bf,
        1536, xd, (long)Bc * xd, (long)1536 * xd, 1536, (long)Bc * 1536);

    // gh = h[l] @ W_hh[l]^T + b_hh[l]  batched z=8 (2048x1536, K=512) -> bf16
    gemm_bb<true, false><<<dim3(12, 16, 8), 256, 0, stream>>>(
        h_bfl, whh_bf, b_hh + (long)l * Cc * 1536, gh_bf,
        1536, 512, (long)Bc * 512, (long)1536 * 512, 1536, (long)Bc * 1536);

    gru_gate<<<4096, 256, 0, stream>>>(gi_bf, gh_bf, h + (long)l * HN_L,
                                       hn + (long)l * HN_L, hn_bf);
  }

  // y = h_n[3][0] @ head_w^T + head_b  (2048x32000, K=512) -> fp32
  // SWAPXY grid: 16 row-tiles on fast x share each 131 KB B-tile via L2.
  f2b_all<<<8000, 256, 0, stream>>>(head_w, headw_bf, 2048000);
  gemm_bb<false, true><<<dim3(16, 250, 1), 256, 0, stream>>>(
      hn_bf, headw_bf, head_b, y, NCc, 512, 0, 0, 0, 0);
}